// Round 9
// baseline (478.383 us; speedup 1.0000x reference)
//
#include <hip/hip_runtime.h>

#define NB 32
#define NC 511      // T-1 context positions
#define NK 8        // senses (center)
#define NS 8        // senses (context)
#define ND 300      // embedding dim
#define ND4 75      // float4 per row
#define NJ 16       // blocks per b
#define CPW 8       // c's per wave (4 waves/block: block covers 32 c's)
#define NCHK 16     // m~ partials per b (one per block)
#define EPS_COS 1e-8f

// Math notes (verified R1-R8, absmax 0.0):
//  - positional log-weight is constant (dist>=1 -> exp(-1000*d) underflows ->
//    log(EPS)), cancels in softmax over c => center_pos/query_token_ids unused.
//  - cosine(cen,m) is scale-invariant in m => softmax normalization and max-
//    subtraction cancel; accumulate unnormalized m~ = sum_c exp(a_c) * v_c.
//  - R8 post-mortem: batched+NT loads helped ~8us; plateau is wave churn
//    (1 c per wave, exposed latency each wave). R9: persistent waves, 8 c's
//    each, register double-buffer prefetch => loads always in flight; fused
//    accumulate => no v/ea round-trips (157 MB floor instead of 196 MB).

typedef float nfloat4 __attribute__((ext_vector_type(4)));

__device__ __forceinline__ void n4add(nfloat4& a, const nfloat4& b) { a += b; }

__device__ __forceinline__ void load_c(const float* __restrict__ ctx, int b, int c,
                                       int i0, int i1, bool has1,
                                       nfloat4* X, nfloat4* Y) {
    const nfloat4* p = (const nfloat4*)ctx + (size_t)(b * NC + c) * (NS * ND4);
#pragma unroll
    for (int s = 0; s < NS; ++s)
        X[s] = __builtin_nontemporal_load(&p[s * ND4 + i0]);
    if (has1) {
#pragma unroll
        for (int s = 0; s < NS; ++s)
            Y[s] = __builtin_nontemporal_load(&p[s * ND4 + i1]);
    }
}

__device__ __forceinline__ void consume(nfloat4* X, nfloat4* Y,
                                        const nfloat4* cenA,        // i0 half, regs
                                        const nfloat4* cen4,        // global, for i1 half
                                        int i0, int i1, bool has1, bool active,
                                        nfloat4* acc0, nfloat4* acc1) {
    // tree mean
    n4add(X[0], X[1]); n4add(X[2], X[3]); n4add(X[4], X[5]); n4add(X[6], X[7]);
    n4add(X[0], X[2]); n4add(X[4], X[6]);
    n4add(X[0], X[4]);
    n4add(Y[0], Y[1]); n4add(Y[2], Y[3]); n4add(Y[4], Y[5]); n4add(Y[6], Y[7]);
    n4add(Y[0], Y[2]); n4add(Y[4], Y[6]);
    n4add(Y[0], Y[4]);
    const float inv = 0.125f;              // 1/S
    nfloat4 s0 = X[0] * inv;
    nfloat4 s1 = Y[0] * inv;

    float pk[NK];
#pragma unroll
    for (int k = 0; k < NK; ++k) {
        nfloat4 ca = cenA[k];
        float p = ca.x * s0.x + ca.y * s0.y + ca.z * s0.z + ca.w * s0.w;
        if (has1) {
            nfloat4 cb = cen4[k * ND4 + i1];   // L1-resident reload (saves VGPRs)
            p += cb.x * s1.x + cb.y * s1.y + cb.z * s1.z + cb.w * s1.w;
        }
        pk[k] = p;
    }
#pragma unroll
    for (int off = 32; off; off >>= 1) {
#pragma unroll
        for (int k = 0; k < NK; ++k) pk[k] += __shfl_xor(pk[k], off);
    }
    if (active) {
        const float scale = 0.057735026919f;   // 1/sqrt(300)
#pragma unroll
        for (int k = 0; k < NK; ++k) {
            float wk = __expf(pk[k] * scale);
            acc0[k] += wk * s0;
            if (has1) acc1[k] += wk * s1;
        }
    }
}

// ---------------------------------------------------------------------------
// K1: block = (b, j); 4 waves x 8 c's each, register-double-buffered prefetch.
// Per c: mean over senses -> v (regs only); 8 dots vs cen; butterfly; 
// acc_k += exp(a_k/sqrt(d)) * v. 2-stage LDS tree merge -> one partial/block.
// ---------------------------------------------------------------------------
__global__ __launch_bounds__(256, 2) void k_main(const float* __restrict__ ctx,
                                                 const float* __restrict__ cen,
                                                 float* __restrict__ part) {
    const int b    = blockIdx.x >> 4;
    const int j    = blockIdx.x & 15;
    const int w    = threadIdx.x >> 6;     // wave 0..3
    const int lane = threadIdx.x & 63;
    const int i0 = lane;
    const int i1 = lane + 64;
    const bool has1 = (i1 < ND4);          // lanes 0..10 own a second float4
    const int cbase = j * 32 + w * CPW;

    const nfloat4* cen4 = (const nfloat4*)cen + (size_t)b * NK * ND4;
    nfloat4 cenA[NK];
#pragma unroll
    for (int k = 0; k < NK; ++k) cenA[k] = cen4[k * ND4 + i0];

    nfloat4 acc0[NK] = {};
    nfloat4 acc1[NK] = {};
    nfloat4 XA[NS], YA[NS] = {}, XB[NS], YB[NS] = {};

    // prefetch c0, then: issue c+1 into alternate buffer BEFORE consuming c
    load_c(ctx, b, min(cbase, NC - 1), i0, i1, has1, XA, YA);
#pragma unroll
    for (int i = 0; i < CPW; ++i) {
        const int c = cbase + i;
        nfloat4* Xc = (i & 1) ? XB : XA;
        nfloat4* Yc = (i & 1) ? YB : YA;
        nfloat4* Xn = (i & 1) ? XA : XB;
        nfloat4* Yn = (i & 1) ? YA : YB;
        if (i + 1 < CPW)
            load_c(ctx, b, min(c + 1, NC - 1), i0, i1, has1, Xn, Yn);
        consume(Xc, Yc, cenA, cen4, i0, i1, has1, c < NC, acc0, acc1);
    }

    // ---- 2-stage tree merge over 4 waves ----
    __shared__ nfloat4 slab[2 * NK * ND4];   // 19.2 KB
#define SLAB_ST(slot) { nfloat4* sp = slab + (slot) * NK * ND4;                 \
    _Pragma("unroll") for (int k = 0; k < NK; ++k) {                            \
        sp[k * ND4 + i0] = acc0[k];                                             \
        if (has1) sp[k * ND4 + i1] = acc1[k]; } }
#define SLAB_ADD(slot) { const nfloat4* sp = slab + (slot) * NK * ND4;          \
    _Pragma("unroll") for (int k = 0; k < NK; ++k) {                            \
        acc0[k] += sp[k * ND4 + i0];                                            \
        if (has1) acc1[k] += sp[k * ND4 + i1]; } }

    if (w >= 2) SLAB_ST(w - 2);
    __syncthreads();
    if (w < 2) SLAB_ADD(w);
    __syncthreads();
    if (w == 1) SLAB_ST(0);
    __syncthreads();
    if (w == 0) {
        SLAB_ADD(0);
        nfloat4* pp = (nfloat4*)part + (size_t)(b * NJ + j) * NK * ND4;
#pragma unroll
        for (int k = 0; k < NK; ++k) {
            pp[k * ND4 + i0] = acc0[k];
            if (has1) pp[k * ND4 + i1] = acc1[k];
        }
    }
#undef SLAB_ST
#undef SLAB_ADD
}

// ---------------------------------------------------------------------------
// K2: block = (b,k), 320 threads. Sum 16 chunk-partials along d, then block-
// reduce the cosine terms -> s[b,k].
// ---------------------------------------------------------------------------
__global__ __launch_bounds__(320) void k_red(const float* __restrict__ part,
                                             const float* __restrict__ cen,
                                             float* __restrict__ sv) {
    const int b = blockIdx.x >> 3;
    const int k = blockIdx.x & 7;
    const int t = threadIdx.x;
    const int lane = t & 63, w = t >> 6;

    float m = 0.f;
    float cv = 0.f;
    if (t < ND) {
        const float* p = part + ((size_t)(b * NCHK) * NK + k) * ND + t;
#pragma unroll
        for (int ch = 0; ch < NCHK; ++ch)
            m += p[(size_t)ch * NK * ND];
        cv = cen[(size_t)(b * NK + k) * ND + t];
    }
    float num = cv * m, n1 = cv * cv, n2 = m * m;
#pragma unroll
    for (int off = 32; off; off >>= 1) {
        num += __shfl_down(num, off);
        n1  += __shfl_down(n1, off);
        n2  += __shfl_down(n2, off);
    }
    __shared__ float red[5][3];
    if (lane == 0) { red[w][0] = num; red[w][1] = n1; red[w][2] = n2; }
    __syncthreads();
    if (t == 0) {
        float a0 = 0.f, a1 = 0.f, a2 = 0.f;
#pragma unroll
        for (int i = 0; i < 5; ++i) { a0 += red[i][0]; a1 += red[i][1]; a2 += red[i][2]; }
        float denom = fmaxf(sqrtf(a1), EPS_COS) * fmaxf(sqrtf(a2), EPS_COS);
        sv[b * NK + k] = a0 / denom;
    }
}

// ---------------------------------------------------------------------------
// K3: per b — q softmax over 8, first-max argmax, write q and pooled row.
// ---------------------------------------------------------------------------
__global__ __launch_bounds__(256) void k_fin(const float* __restrict__ sv,
                                             const float* __restrict__ cen,
                                             float* __restrict__ out) {
    const int b = blockIdx.x;
    const int t = threadIdx.x;
    __shared__ int bidx;
    if (t == 0) {
        float s[NK];
#pragma unroll
        for (int k = 0; k < NK; ++k) s[k] = sv[b * NK + k];
        float mx = s[0];
#pragma unroll
        for (int k = 1; k < NK; ++k) mx = fmaxf(mx, s[k]);
        float e[NK], sum = 0.f;
#pragma unroll
        for (int k = 0; k < NK; ++k) { e[k] = __expf(s[k] - mx); sum += e[k]; }
        float inv = 1.f / sum;
        int best = 0; float bv = s[0];
#pragma unroll
        for (int k = 1; k < NK; ++k) if (s[k] > bv) { bv = s[k]; best = k; }
#pragma unroll
        for (int k = 0; k < NK; ++k)
            out[(size_t)NB * ND + b * NK + k] = e[k] * inv;
        bidx = best;
    }
    __syncthreads();
    const float* src = cen + (size_t)(b * NK + bidx) * ND;
    for (int idx = t; idx < ND; idx += 256)
        out[(size_t)b * ND + idx] = src[idx];
}

extern "C" void kernel_launch(void* const* d_in, const int* in_sizes, int n_in,
                              void* d_out, int out_size, void* d_ws, size_t ws_size,
                              hipStream_t stream) {
    // d_in[0]=center_pos, d_in[1]=query_token_ids: unused (log-weight constant)
    const float* cen = (const float*)d_in[2];   // [B,K,d]
    const float* ctx = (const float*)d_in[3];   // [B,C,S,d]
    float* out = (float*)d_out;                 // pooled [B,d] then q [B,K]

    float* part = (float*)d_ws;                        // [B][NJ][K][d] = 4.9 MB
    float* sv   = part + (size_t)NB * NCHK * NK * ND;  // [B][K]

    k_main<<<dim3(NB * NJ), dim3(256), 0, stream>>>(ctx, cen, part);
    k_red<<<dim3(NB * NK), dim3(320), 0, stream>>>(part, cen, sv);
    k_fin<<<dim3(NB), dim3(256), 0, stream>>>(sv, cen, out);
}

// Round 10
// 289.305 us; speedup vs baseline: 1.6536x; 1.6536x over previous
//
#include <hip/hip_runtime.h>

#define NB 32
#define NC 511      // T-1 context positions
#define NK 8        // senses (center)
#define NS 8        // senses (context)
#define ND 300      // embedding dim
#define ND4 75      // float4 per row
#define NCH 16      // c-chunks for m-tilde partials
#define CCHUNK 32
#define EPS_COS 1e-8f

// Math notes (verified R1-R9, absmax 0.0):
//  - positional log-weight constant => center_pos/query_token_ids unused.
//  - cosine scale-invariance => no softmax normalization; m~ = sum exp(a)*v.
//  - R9 post-mortem: register double-buffer spilled (VGPR capped 128,
//    WRITE_SIZE 546 MB scratch traffic). Law: in-flight VGPR x waves ~
//    conserved; R8's simple batched structure is the best measured.
//  - R10 = MEASUREMENT ROUND: exact R8, but k_va grid x2 (two interleaved
//    copies, bit-identical redundant writes) so its dispatch exceeds the
//    91us top-5 cutoff and we finally see FETCH/WRITE/VGPR/Occ for it.

typedef float nfloat4 __attribute__((ext_vector_type(4)));

__device__ __forceinline__ void n4add(nfloat4& a, const nfloat4& b) { a += b; }

// ---------------------------------------------------------------------------
// K1: one wave per (b,c) [x2 redundant copies]. Batched NT loads -> tree mean
// -> v; 8 dots vs cen; butterfly; ea = exp(a/sqrt(d)).
// ---------------------------------------------------------------------------
__global__ __launch_bounds__(256) void k_va(const float* __restrict__ ctx,
                                            const float* __restrict__ cen,
                                            float* __restrict__ v,
                                            float* __restrict__ ea) {
    const int blk  = blockIdx.x >> 1;        // copy id = blockIdx.x & 1 (ignored)
    const int b    = blk >> 7;               // 128 blocks per b
    const int cgrp = blk & 127;
    const int w    = threadIdx.x >> 6;       // 4 waves -> 4 c's
    const int lane = threadIdx.x & 63;
    const int c = cgrp * 4 + w;
    if (c >= NC) return;                     // wave-uniform

    const nfloat4* ctx4 = (const nfloat4*)ctx + (size_t)(b * NC + c) * NS * ND4;
    const int i0 = lane;
    const int i1 = lane + 64;
    const bool has1 = (i1 < ND4);            // lanes 0..10 own a second float4

    // ---- batched loads: 8 unmasked, then one exec-toggle block of 8 ----
    nfloat4 X[NS];
#pragma unroll
    for (int s = 0; s < NS; ++s)
        X[s] = __builtin_nontemporal_load(&ctx4[s * ND4 + i0]);
    nfloat4 Y[NS] = {};
    if (has1) {
#pragma unroll
        for (int s = 0; s < NS; ++s)
            Y[s] = __builtin_nontemporal_load(&ctx4[s * ND4 + i1]);
    }

    // ---- tree mean ----
    n4add(X[0], X[1]); n4add(X[2], X[3]); n4add(X[4], X[5]); n4add(X[6], X[7]);
    n4add(X[0], X[2]); n4add(X[4], X[6]);
    n4add(X[0], X[4]);
    n4add(Y[0], Y[1]); n4add(Y[2], Y[3]); n4add(Y[4], Y[5]); n4add(Y[6], Y[7]);
    n4add(Y[0], Y[2]); n4add(Y[4], Y[6]);
    n4add(Y[0], Y[4]);
    const float inv = 0.125f;                // 1/S
    nfloat4 s0 = X[0] * inv;
    nfloat4 s1 = Y[0] * inv;

    nfloat4* v4 = (nfloat4*)v + (size_t)(b * NC + c) * ND4;
    v4[i0] = s0;
    if (has1) v4[i1] = s1;

    // ---- 8 dots vs cen (L1-resident after first block) ----
    const nfloat4* cen4 = (const nfloat4*)cen + (size_t)b * NK * ND4;
    float pk[NK];
#pragma unroll
    for (int k = 0; k < NK; ++k) {
        nfloat4 ca = cen4[k * ND4 + i0];
        float p = ca.x * s0.x + ca.y * s0.y + ca.z * s0.z + ca.w * s0.w;
        if (has1) {
            nfloat4 cb = cen4[k * ND4 + i1];
            p += cb.x * s1.x + cb.y * s1.y + cb.z * s1.z + cb.w * s1.w;
        }
        pk[k] = p;
    }
#pragma unroll
    for (int off = 32; off; off >>= 1) {
#pragma unroll
        for (int k = 0; k < NK; ++k) pk[k] += __shfl_down(pk[k], off);
    }
    if (lane == 0) {
        const float scale = 0.057735026919f; // 1/sqrt(300)
#pragma unroll
        for (int k = 0; k < NK; ++k)
            ea[(size_t)(b * NK + k) * NC + c] = __expf(pk[k] * scale);
    }
}

// ---------------------------------------------------------------------------
// K2: m~ partials over c-chunks: part[ch,b,k,:] = sum_{c in chunk} ea * v[b,c,:].
// ---------------------------------------------------------------------------
__global__ __launch_bounds__(320) void k_m(const float* __restrict__ v,
                                           const float* __restrict__ ea,
                                           float* __restrict__ part) {
    int b  = blockIdx.x >> 4;
    int ch = blockIdx.x & 15;
    int c0 = ch * CCHUNK;
    int cn = min(CCHUNK, NC - c0);
    __shared__ float al[NK][CCHUNK];
    int t = threadIdx.x;
    if (t < NK * CCHUNK) {             // 256 loads
        int k = t >> 5, cc = t & 31;
        al[k][cc] = (cc < cn) ? ea[(size_t)(b * NK + k) * NC + c0 + cc] : 0.f;
    }
    __syncthreads();
    if (t < ND) {
        float acc[NK] = {0.f, 0.f, 0.f, 0.f, 0.f, 0.f, 0.f, 0.f};
        const float* vp = v + ((size_t)b * NC + c0) * ND + t;
        for (int cc = 0; cc < cn; ++cc) {
            float vv = vp[(size_t)cc * ND];
#pragma unroll
            for (int k = 0; k < NK; ++k) acc[k] += al[k][cc] * vv;
        }
        float* pp = part + ((size_t)(ch * NB + b) * NK) * ND + t;
#pragma unroll
        for (int k = 0; k < NK; ++k) pp[(size_t)k * ND] = acc[k];
    }
}

// ---------------------------------------------------------------------------
// K3: per b — sum m~ partials into LDS, cosine per k, q softmax, argmax, write.
// ---------------------------------------------------------------------------
__global__ __launch_bounds__(256) void k_final(const float* __restrict__ part,
                                               const float* __restrict__ cen,
                                               float* __restrict__ out) {
    int b = blockIdx.x;
    __shared__ float m[NK * ND];
    __shared__ float sred[NK];
    __shared__ int bidx;
    int t = threadIdx.x;

    for (int idx = t; idx < NK * ND; idx += 256) {
        float s = 0.f;
#pragma unroll
        for (int ch = 0; ch < NCH; ++ch)
            s += part[(size_t)(ch * NB + b) * NK * ND + idx];
        m[idx] = s;
    }
    __syncthreads();

    int w = t >> 6, lane = t & 63;
#pragma unroll
    for (int kk = 0; kk < 2; ++kk) {
        int k = w + kk * 4;
        const float* cp = cen + (size_t)(b * NK + k) * ND;
        const float* mp = m + k * ND;
        float num = 0.f, n1 = 0.f, n2 = 0.f;
        for (int dd = lane; dd < ND; dd += 64) {
            float cv = cp[dd], mv = mp[dd];
            num += cv * mv; n1 += cv * cv; n2 += mv * mv;
        }
#pragma unroll
        for (int off = 32; off; off >>= 1) {
            num += __shfl_down(num, off);
            n1  += __shfl_down(n1, off);
            n2  += __shfl_down(n2, off);
        }
        if (lane == 0) {
            float denom = fmaxf(sqrtf(n1), EPS_COS) * fmaxf(sqrtf(n2), EPS_COS);
            sred[k] = num / denom;
        }
    }
    __syncthreads();

    if (t == 0) {
        float mx = sred[0];
#pragma unroll
        for (int k = 1; k < NK; ++k) mx = fmaxf(mx, sred[k]);
        float e[NK], sum = 0.f;
#pragma unroll
        for (int k = 0; k < NK; ++k) { e[k] = __expf(sred[k] - mx); sum += e[k]; }
        float inv = 1.f / sum;
        int best = 0; float bv = sred[0];
#pragma unroll
        for (int k = 1; k < NK; ++k) if (sred[k] > bv) { bv = sred[k]; best = k; }
#pragma unroll
        for (int k = 0; k < NK; ++k)
            out[(size_t)NB * ND + b * NK + k] = e[k] * inv;
        bidx = best;
    }
    __syncthreads();

    const float* src = cen + (size_t)(b * NK + bidx) * ND;
    for (int idx = t; idx < ND; idx += 256)
        out[(size_t)b * ND + idx] = src[idx];
}

extern "C" void kernel_launch(void* const* d_in, const int* in_sizes, int n_in,
                              void* d_out, int out_size, void* d_ws, size_t ws_size,
                              hipStream_t stream) {
    // d_in[0]=center_pos, d_in[1]=query_token_ids: unused (log-weight constant)
    const float* cen = (const float*)d_in[2];   // [B,K,d]
    const float* ctx = (const float*)d_in[3];   // [B,C,S,d]
    float* out = (float*)d_out;                 // pooled [B,d] then q [B,K]

    float* v    = (float*)d_ws;                      // B*C*D     floats
    float* ea   = v + (size_t)NB * NC * ND;          // B*K*C     floats
    float* part = ea + (size_t)NB * NK * NC;         // NCH*B*K*D floats

    // MEASUREMENT: grid x2 — two interleaved copies, identical redundant
    // writes, pushes the k_va dispatch over the 91us top-5 counter cutoff.
    k_va<<<dim3(NB * 128 * 2), dim3(256), 0, stream>>>(ctx, cen, v, ea);
    k_m<<<dim3(NB * NCH), dim3(320), 0, stream>>>(v, ea, part);
    k_final<<<dim3(NB), dim3(256), 0, stream>>>(part, cen, out);
}

// Round 11
// 255.698 us; speedup vs baseline: 1.8709x; 1.1314x over previous
//
#include <hip/hip_runtime.h>

#define NB 32
#define NC 511      // T-1 context positions
#define NK 8        // senses (center)
#define NS 8        // senses (context)
#define ND 300      // embedding dim
#define ND4 75      // float4 per row
#define NCH 32      // c-chunks for m-tilde partials
#define CCHUNK 16
#define EPS_COS 1e-8f

// Math notes (verified R1-R10, absmax 0.0):
//  - positional log-weight constant => center_pos/query_token_ids unused.
//  - cosine scale-invariance => no softmax normalization; m~ = sum exp(a)*v.
//  - R10 measurement: k_va VGPR=40 (compiler recycles load dests, ~10 loads
//    in flight/wave -> 3 KB/CU -> 2.3 TB/s, matches model). Marginal BW of
//    extra concurrent c-work = 5 TB/s => raise per-wave batch to 2 c's
//    (32 loads issued before any consume, cen reused across both).

typedef float nfloat4 __attribute__((ext_vector_type(4)));

__device__ __forceinline__ void n4add(nfloat4& a, const nfloat4& b) { a += b; }

// ---------------------------------------------------------------------------
// K1: 2 c's per wave. Block=(b, j of 64): wave w owns c0=j*8+w*2, c1=c0+1.
// All 32 NT loads issued up front; tree means; 8 cen fragments loaded once
// and dotted against BOTH c's; butterflies; ea = exp(a/sqrt(d)); v stores.
// ---------------------------------------------------------------------------
__global__ __launch_bounds__(256) void k_va(const float* __restrict__ ctx,
                                            const float* __restrict__ cen,
                                            float* __restrict__ v,
                                            float* __restrict__ ea) {
    const int b    = blockIdx.x >> 6;        // 64 blocks per b
    const int j    = blockIdx.x & 63;
    const int w    = threadIdx.x >> 6;       // 4 waves
    const int lane = threadIdx.x & 63;
    const int c0 = j * 8 + w * 2;            // 0..510
    const int c1 = c0 + 1;
    const bool h1 = (c1 < NC);               // wave-uniform (false only j=63,w=3)

    const int i0 = lane;
    const int i1 = lane + 64;
    const bool has1 = (i1 < ND4);            // lanes 0..10 own a second float4

    const nfloat4* p0 = (const nfloat4*)ctx + (size_t)(b * NC + c0) * (NS * ND4);
    const nfloat4* p1 = (const nfloat4*)ctx + (size_t)(b * NC + (h1 ? c1 : c0)) * (NS * ND4);

    // ---- 32 batched NT loads: both c's before any arithmetic ----
    nfloat4 X0[NS], X1[NS];
#pragma unroll
    for (int s = 0; s < NS; ++s)
        X0[s] = __builtin_nontemporal_load(&p0[s * ND4 + i0]);
#pragma unroll
    for (int s = 0; s < NS; ++s)
        X1[s] = __builtin_nontemporal_load(&p1[s * ND4 + i0]);
    nfloat4 Y0[NS] = {}, Y1[NS] = {};
    if (has1) {
#pragma unroll
        for (int s = 0; s < NS; ++s)
            Y0[s] = __builtin_nontemporal_load(&p0[s * ND4 + i1]);
#pragma unroll
        for (int s = 0; s < NS; ++s)
            Y1[s] = __builtin_nontemporal_load(&p1[s * ND4 + i1]);
    }

    // ---- tree means ----
    n4add(X0[0], X0[1]); n4add(X0[2], X0[3]); n4add(X0[4], X0[5]); n4add(X0[6], X0[7]);
    n4add(X0[0], X0[2]); n4add(X0[4], X0[6]); n4add(X0[0], X0[4]);
    n4add(X1[0], X1[1]); n4add(X1[2], X1[3]); n4add(X1[4], X1[5]); n4add(X1[6], X1[7]);
    n4add(X1[0], X1[2]); n4add(X1[4], X1[6]); n4add(X1[0], X1[4]);
    n4add(Y0[0], Y0[1]); n4add(Y0[2], Y0[3]); n4add(Y0[4], Y0[5]); n4add(Y0[6], Y0[7]);
    n4add(Y0[0], Y0[2]); n4add(Y0[4], Y0[6]); n4add(Y0[0], Y0[4]);
    n4add(Y1[0], Y1[1]); n4add(Y1[2], Y1[3]); n4add(Y1[4], Y1[5]); n4add(Y1[6], Y1[7]);
    n4add(Y1[0], Y1[2]); n4add(Y1[4], Y1[6]); n4add(Y1[0], Y1[4]);
    const float inv = 0.125f;                // 1/S
    nfloat4 a0 = X0[0] * inv, b0 = Y0[0] * inv;   // c0: i0 / i1 halves
    nfloat4 a1 = X1[0] * inv, b1 = Y1[0] * inv;   // c1

    nfloat4* v40 = (nfloat4*)v + (size_t)(b * NC + c0) * ND4;
    v40[i0] = a0;
    if (has1) v40[i1] = b0;
    if (h1) {
        nfloat4* v41 = (nfloat4*)v + (size_t)(b * NC + c1) * ND4;
        v41[i0] = a1;
        if (has1) v41[i1] = b1;
    }

    // ---- 8 cen fragments, each dotted vs both c's (L1-resident) ----
    const nfloat4* cen4 = (const nfloat4*)cen + (size_t)b * NK * ND4;
    float pk0[NK], pk1[NK];
#pragma unroll
    for (int k = 0; k < NK; ++k) {
        nfloat4 ca = cen4[k * ND4 + i0];
        float q0 = ca.x * a0.x + ca.y * a0.y + ca.z * a0.z + ca.w * a0.w;
        float q1 = ca.x * a1.x + ca.y * a1.y + ca.z * a1.z + ca.w * a1.w;
        if (has1) {
            nfloat4 cb = cen4[k * ND4 + i1];
            q0 += cb.x * b0.x + cb.y * b0.y + cb.z * b0.z + cb.w * b0.w;
            q1 += cb.x * b1.x + cb.y * b1.y + cb.z * b1.z + cb.w * b1.w;
        }
        pk0[k] = q0; pk1[k] = q1;
    }
#pragma unroll
    for (int off = 32; off; off >>= 1) {
#pragma unroll
        for (int k = 0; k < NK; ++k) {
            pk0[k] += __shfl_down(pk0[k], off);
            pk1[k] += __shfl_down(pk1[k], off);
        }
    }
    if (lane == 0) {
        const float scale = 0.057735026919f; // 1/sqrt(300)
#pragma unroll
        for (int k = 0; k < NK; ++k) {
            ea[(size_t)(b * NK + k) * NC + c0] = __expf(pk0[k] * scale);
            if (h1) ea[(size_t)(b * NK + k) * NC + c1] = __expf(pk1[k] * scale);
        }
    }
}

// ---------------------------------------------------------------------------
// K2: m~ partials over c-chunks: part[ch,b,k,:] = sum_{c in chunk} ea * v[b,c,:].
// 1024 blocks, 16-c chunks (shorter serial loops -> better latency overlap).
// ---------------------------------------------------------------------------
__global__ __launch_bounds__(320) void k_m(const float* __restrict__ v,
                                           const float* __restrict__ ea,
                                           float* __restrict__ part) {
    int b  = blockIdx.x >> 5;
    int ch = blockIdx.x & 31;
    int c0 = ch * CCHUNK;
    int cn = min(CCHUNK, NC - c0);
    __shared__ float al[NK][CCHUNK];
    int t = threadIdx.x;
    if (t < NK * CCHUNK) {             // 128 loads
        int k = t >> 4, cc = t & 15;
        al[k][cc] = (cc < cn) ? ea[(size_t)(b * NK + k) * NC + c0 + cc] : 0.f;
    }
    __syncthreads();
    if (t < ND) {
        float acc[NK] = {0.f, 0.f, 0.f, 0.f, 0.f, 0.f, 0.f, 0.f};
        const float* vp = v + ((size_t)b * NC + c0) * ND + t;
#pragma unroll
        for (int cc = 0; cc < CCHUNK; ++cc) {
            if (cc < cn) {
                float vv = vp[(size_t)cc * ND];
#pragma unroll
                for (int k = 0; k < NK; ++k) acc[k] += al[k][cc] * vv;
            }
        }
        float* pp = part + ((size_t)(ch * NB + b) * NK) * ND + t;
#pragma unroll
        for (int k = 0; k < NK; ++k) pp[(size_t)k * ND] = acc[k];
    }
}

// ---------------------------------------------------------------------------
// K3: per b — sum m~ partials into LDS, cosine per k, q softmax, argmax, write.
// ---------------------------------------------------------------------------
__global__ __launch_bounds__(256) void k_final(const float* __restrict__ part,
                                               const float* __restrict__ cen,
                                               float* __restrict__ out) {
    int b = blockIdx.x;
    __shared__ float m[NK * ND];
    __shared__ float sred[NK];
    __shared__ int bidx;
    int t = threadIdx.x;

    for (int idx = t; idx < NK * ND; idx += 256) {
        float s = 0.f;
#pragma unroll
        for (int ch = 0; ch < NCH; ++ch)
            s += part[(size_t)(ch * NB + b) * NK * ND + idx];
        m[idx] = s;
    }
    __syncthreads();

    int w = t >> 6, lane = t & 63;
#pragma unroll
    for (int kk = 0; kk < 2; ++kk) {
        int k = w + kk * 4;
        const float* cp = cen + (size_t)(b * NK + k) * ND;
        const float* mp = m + k * ND;
        float num = 0.f, n1 = 0.f, n2 = 0.f;
        for (int dd = lane; dd < ND; dd += 64) {
            float cv = cp[dd], mv = mp[dd];
            num += cv * mv; n1 += cv * cv; n2 += mv * mv;
        }
#pragma unroll
        for (int off = 32; off; off >>= 1) {
            num += __shfl_down(num, off);
            n1  += __shfl_down(n1, off);
            n2  += __shfl_down(n2, off);
        }
        if (lane == 0) {
            float denom = fmaxf(sqrtf(n1), EPS_COS) * fmaxf(sqrtf(n2), EPS_COS);
            sred[k] = num / denom;
        }
    }
    __syncthreads();

    if (t == 0) {
        float mx = sred[0];
#pragma unroll
        for (int k = 1; k < NK; ++k) mx = fmaxf(mx, sred[k]);
        float e[NK], sum = 0.f;
#pragma unroll
        for (int k = 0; k < NK; ++k) { e[k] = __expf(sred[k] - mx); sum += e[k]; }
        float inv = 1.f / sum;
        int best = 0; float bv = sred[0];
#pragma unroll
        for (int k = 1; k < NK; ++k) if (sred[k] > bv) { bv = sred[k]; best = k; }
#pragma unroll
        for (int k = 0; k < NK; ++k)
            out[(size_t)NB * ND + b * NK + k] = e[k] * inv;
        bidx = best;
    }
    __syncthreads();

    const float* src = cen + (size_t)(b * NK + bidx) * ND;
    for (int idx = t; idx < ND; idx += 256)
        out[(size_t)b * ND + idx] = src[idx];
}

extern "C" void kernel_launch(void* const* d_in, const int* in_sizes, int n_in,
                              void* d_out, int out_size, void* d_ws, size_t ws_size,
                              hipStream_t stream) {
    // d_in[0]=center_pos, d_in[1]=query_token_ids: unused (log-weight constant)
    const float* cen = (const float*)d_in[2];   // [B,K,d]
    const float* ctx = (const float*)d_in[3];   // [B,C,S,d]
    float* out = (float*)d_out;                 // pooled [B,d] then q [B,K]

    float* v    = (float*)d_ws;                      // B*C*D     floats
    float* ea   = v + (size_t)NB * NC * ND;          // B*K*C     floats
    float* part = ea + (size_t)NB * NK * NC;         // NCH*B*K*D floats (9.8 MB)

    k_va<<<dim3(NB * 64), dim3(256), 0, stream>>>(ctx, cen, v, ea);
    k_m<<<dim3(NB * NCH), dim3(320), 0, stream>>>(v, ea, part);
    k_final<<<dim3(NB), dim3(256), 0, stream>>>(part, cen, out);
}